// Round 1
// baseline (115.637 us; speedup 1.0000x reference)
//
#include <hip/hip_runtime.h>
#include <math.h>

// GLIF forward: out[t] = heaviside(u_t - Vth_s), u_t recurrence over T.
// One thread owns 4 consecutive channels (float4) of one batch row and
// iterates t privately. Memory-bound: 256MB in + 256MB out.

__device__ __forceinline__ float sigmoidf_acc(float v) {
    // accurate sigmoid, matches numpy's 1/(1+exp(-x)) to ~1 ulp
    return 1.0f / (1.0f + expf(-v));
}

__global__ __launch_bounds__(256) void glif_fwd_kernel(
    const float* __restrict__ x,
    const float* __restrict__ tau,
    const float* __restrict__ Vth,
    const float* __restrict__ leak,
    const float* __restrict__ reVth,
    const float* __restrict__ conduct,
    const float* __restrict__ alpha,
    const float* __restrict__ beta,
    const float* __restrict__ gamma_,
    float* __restrict__ out,
    int BC4,   // B*C/4  (total float4 lanes per time slice)
    int C4,    // C/4
    int T)
{
#pragma clang fp contract(off)
    int idx = blockIdx.x * blockDim.x + threadIdx.x;
    if (idx >= BC4) return;
    int c4 = idx & (C4 - 1);   // C4 is a power of two (256)

    // ---- per-channel derived params (4 channels per thread) ----
    const float4 alv = reinterpret_cast<const float4*>(alpha)[c4];
    const float4 bev = reinterpret_cast<const float4*>(beta )[c4];
    const float4 gav = reinterpret_cast<const float4*>(gamma_)[c4];
    const float4 tav = reinterpret_cast<const float4*>(tau  )[c4];
    const float4 vtv = reinterpret_cast<const float4*>(Vth  )[c4];
    const float4 lkv = reinterpret_cast<const float4*>(leak )[c4];
    const float4 rvv = reinterpret_cast<const float4*>(reVth)[c4];

    float al[4] = { alv.x > 0.0f ? 1.0f : 0.0f, alv.y > 0.0f ? 1.0f : 0.0f,
                    alv.z > 0.0f ? 1.0f : 0.0f, alv.w > 0.0f ? 1.0f : 0.0f };
    float be[4] = { bev.x > 0.0f ? 1.0f : 0.0f, bev.y > 0.0f ? 1.0f : 0.0f,
                    bev.z > 0.0f ? 1.0f : 0.0f, bev.w > 0.0f ? 1.0f : 0.0f };
    float ga[4] = { gav.x > 0.0f ? 1.0f : 0.0f, gav.y > 0.0f ? 1.0f : 0.0f,
                    gav.z > 0.0f ? 1.0f : 0.0f, gav.w > 0.0f ? 1.0f : 0.0f };
    float ta[4] = { tav.x, tav.y, tav.z, tav.w };
    float vt[4] = { vtv.x, vtv.y, vtv.z, vtv.w };
    float lk[4] = { lkv.x, lkv.y, lkv.z, lkv.w };
    float rv[4] = { rvv.x, rvv.y, rvv.z, rvv.w };

    float decay[4], leakt[4], vth_s[4], rvc[4];
    #pragma unroll
    for (int j = 0; j < 4; ++j) {
        float tau_s   = sigmoidf_acc(ta[j]);
        float vth_sj  = sigmoidf_acc(vt[j]);
        float leak_s  = sigmoidf_acc(lk[j]);
        float reVth_s = sigmoidf_acc(rv[j]);
        decay[j] = 1.0f - al[j] * (1.0f - tau_s);   // same expr order as ref
        leakt[j] = (1.0f - al[j]) * leak_s;
        vth_s[j] = vth_sj;
        rvc[j]   = (1.0f - ga[j]) * reVth_s;        // ((1-ga)*reVth_s)
    }

    // ---- scan over T ----
    float u[4] = {0.0f, 0.0f, 0.0f, 0.0f};
    float o[4] = {0.0f, 0.0f, 0.0f, 0.0f};

    const float4* __restrict__ x4 = reinterpret_cast<const float4*>(x);
    const float4* __restrict__ cd4 = reinterpret_cast<const float4*>(conduct);
    float4* __restrict__ o4 = reinterpret_cast<float4*>(out);

    for (int t = 0; t < T; ++t) {
        size_t off = (size_t)t * (size_t)BC4 + (size_t)idx;
        float4 xv = x4[off];
        float4 cv = cd4[(size_t)t * (size_t)C4 + (size_t)c4];   // tiny, L2/L1-hot

        float xs[4] = { xv.x, xv.y, xv.z, xv.w };
        float cs[4] = { cv.x, cv.y, cv.z, cv.w };
        float os[4];

        #pragma unroll
        for (int j = 0; j < 4; ++j) {
            float ct = sigmoidf_acc(cs[j]);
            float I  = xs[j] * (1.0f - be[j] * (1.0f - ct));
            // ref order: decay*u*(1-ga*o) - leak_term + I - ((1-ga)*reVth_s)*o
            float un = decay[j] * u[j] * (1.0f - ga[j] * o[j]) - leakt[j] + I
                       - rvc[j] * o[j];
            float on = (un - vth_s[j] >= 0.0f) ? 1.0f : 0.0f;
            u[j] = un;
            o[j] = on;
            os[j] = on;
        }

        float4 ov;
        ov.x = os[0]; ov.y = os[1]; ov.z = os[2]; ov.w = os[3];
        o4[off] = ov;
    }
}

extern "C" void kernel_launch(void* const* d_in, const int* in_sizes, int n_in,
                              void* d_out, int out_size, void* d_ws, size_t ws_size,
                              hipStream_t stream) {
    const float* x       = (const float*)d_in[0];
    const float* tau     = (const float*)d_in[1];
    const float* Vth     = (const float*)d_in[2];
    const float* leak    = (const float*)d_in[3];
    const float* reVth   = (const float*)d_in[4];
    const float* conduct = (const float*)d_in[5];
    const float* alpha   = (const float*)d_in[6];
    const float* beta    = (const float*)d_in[7];
    const float* gamma_  = (const float*)d_in[8];
    float* out = (float*)d_out;

    const int C  = in_sizes[1];            // 1024
    const int T  = in_sizes[5] / C;        // 16
    const long long BC = (long long)in_sizes[0] / T;  // B*C
    const int BC4 = (int)(BC / 4);
    const int C4  = C / 4;

    const int block = 256;
    const int grid  = (BC4 + block - 1) / block;

    glif_fwd_kernel<<<grid, block, 0, stream>>>(
        x, tau, Vth, leak, reVth, conduct, alpha, beta, gamma_,
        out, BC4, C4, T);
}

// Round 3
// 110.027 us; speedup vs baseline: 1.0510x; 1.0510x over previous
//
#include <hip/hip_runtime.h>
#include <math.h>

// GLIF forward, two-kernel version:
//  K1: iscale[t][c] = 1 - be_c * (1 - sigmoid(conduct[t][c]))  (T*C = 16K vals, into d_ws)
//  K2: scan over T; one thread owns 4 channels of one batch row.
//      No transcendentals in the hot loop; explicit x[t+1] prefetch;
//      nontemporal load/store on the 256MB x/out streams.

typedef float f32x4 __attribute__((ext_vector_type(4)));

__device__ __forceinline__ float sigmoidf_acc(float v) {
    return 1.0f / (1.0f + expf(-v));
}

__global__ __launch_bounds__(256) void glif_iscale_kernel(
    const float* __restrict__ conduct,
    const float* __restrict__ beta,
    float* __restrict__ iscale,
    int TC4, int C4)
{
#pragma clang fp contract(off)
    int idx = blockIdx.x * blockDim.x + threadIdx.x;
    if (idx >= TC4) return;
    int c4 = idx & (C4 - 1);

    const f32x4 bev = reinterpret_cast<const f32x4*>(beta)[c4];
    const f32x4 cv  = reinterpret_cast<const f32x4*>(conduct)[idx];

    f32x4 ov;
    #pragma unroll
    for (int j = 0; j < 4; ++j) {
        float be = bev[j] > 0.0f ? 1.0f : 0.0f;
        float ct = sigmoidf_acc(cv[j]);
        ov[j] = 1.0f - be * (1.0f - ct);   // exact ref expression order
    }
    reinterpret_cast<f32x4*>(iscale)[idx] = ov;
}

__global__ __launch_bounds__(256) void glif_fwd_kernel(
    const float* __restrict__ x,
    const float* __restrict__ tau,
    const float* __restrict__ Vth,
    const float* __restrict__ leak,
    const float* __restrict__ reVth,
    const float* __restrict__ alpha,
    const float* __restrict__ gamma_,
    const float* __restrict__ iscale,
    float* __restrict__ out,
    int BC4, int C4, int T)
{
#pragma clang fp contract(off)
    int idx = blockIdx.x * blockDim.x + threadIdx.x;
    if (idx >= BC4) return;
    int c4 = idx & (C4 - 1);

    const f32x4 alv = reinterpret_cast<const f32x4*>(alpha)[c4];
    const f32x4 gav = reinterpret_cast<const f32x4*>(gamma_)[c4];
    const f32x4 tav = reinterpret_cast<const f32x4*>(tau  )[c4];
    const f32x4 vtv = reinterpret_cast<const f32x4*>(Vth  )[c4];
    const f32x4 lkv = reinterpret_cast<const f32x4*>(leak )[c4];
    const f32x4 rvv = reinterpret_cast<const f32x4*>(reVth)[c4];

    float decay[4], leakt[4], vth_s[4], rvc[4], ga[4];
    #pragma unroll
    for (int j = 0; j < 4; ++j) {
        float al = alv[j] > 0.0f ? 1.0f : 0.0f;
        ga[j]    = gav[j] > 0.0f ? 1.0f : 0.0f;
        float tau_s   = sigmoidf_acc(tav[j]);
        float vth_sj  = sigmoidf_acc(vtv[j]);
        float leak_s  = sigmoidf_acc(lkv[j]);
        float reVth_s = sigmoidf_acc(rvv[j]);
        decay[j] = 1.0f - al * (1.0f - tau_s);
        leakt[j] = (1.0f - al) * leak_s;
        vth_s[j] = vth_sj;
        rvc[j]   = (1.0f - ga[j]) * reVth_s;
    }

    float u[4] = {0.0f, 0.0f, 0.0f, 0.0f};
    float o[4] = {0.0f, 0.0f, 0.0f, 0.0f};

    const f32x4* __restrict__ x4  = reinterpret_cast<const f32x4*>(x);
    const f32x4* __restrict__ is4 = reinterpret_cast<const f32x4*>(iscale);
    f32x4* __restrict__ o4 = reinterpret_cast<f32x4*>(out);

    // 1-deep software pipeline on the big x stream
    f32x4 xv = __builtin_nontemporal_load(&x4[idx]);   // t = 0

    for (int t = 0; t < T; ++t) {
        size_t off = (size_t)t * (size_t)BC4 + (size_t)idx;
        f32x4 xn;
        if (t + 1 < T)
            xn = __builtin_nontemporal_load(&x4[off + (size_t)BC4]);

        f32x4 iv = is4[(size_t)t * (size_t)C4 + (size_t)c4];  // L2-hot 64KB

        f32x4 ov;
        #pragma unroll
        for (int j = 0; j < 4; ++j) {
            float I  = xv[j] * iv[j];
            float un = decay[j] * u[j] * (1.0f - ga[j] * o[j]) - leakt[j] + I
                       - rvc[j] * o[j];
            float on = (un - vth_s[j] >= 0.0f) ? 1.0f : 0.0f;
            u[j] = un;
            o[j] = on;
            ov[j] = on;
        }

        __builtin_nontemporal_store(ov, &o4[off]);
        xv = xn;
    }
}

extern "C" void kernel_launch(void* const* d_in, const int* in_sizes, int n_in,
                              void* d_out, int out_size, void* d_ws, size_t ws_size,
                              hipStream_t stream) {
    const float* x       = (const float*)d_in[0];
    const float* tau     = (const float*)d_in[1];
    const float* Vth     = (const float*)d_in[2];
    const float* leak    = (const float*)d_in[3];
    const float* reVth   = (const float*)d_in[4];
    const float* conduct = (const float*)d_in[5];
    const float* alpha   = (const float*)d_in[6];
    const float* beta    = (const float*)d_in[7];
    const float* gamma_  = (const float*)d_in[8];
    float* out = (float*)d_out;

    const int C  = in_sizes[1];                        // 1024
    const int T  = in_sizes[5] / C;                    // 16
    const long long BC = (long long)in_sizes[0] / T;   // B*C
    const int BC4 = (int)(BC / 4);
    const int C4  = C / 4;
    const int TC4 = T * C4;

    const int block = 256;
    const int grid  = (BC4 + block - 1) / block;

    float* iscale = (float*)d_ws;  // needs T*C*4 = 64KB; ws is preallocated scratch
    glif_iscale_kernel<<<(TC4 + block - 1) / block, block, 0, stream>>>(
        conduct, beta, iscale, TC4, C4);
    glif_fwd_kernel<<<grid, block, 0, stream>>>(
        x, tau, Vth, leak, reVth, alpha, gamma_, iscale, out, BC4, C4, T);
}

// Round 4
// 108.644 us; speedup vs baseline: 1.0644x; 1.0127x over previous
//
#include <hip/hip_runtime.h>
#include <math.h>

// GLIF forward, two-kernel version:
//  K1: iscale[t][c] = 1 - be_c * (1 - sigmoid(conduct[t][c]))  (64KB into d_ws)
//  K2: scan over T; one thread owns 4 channels of one batch row.
//      Depth-2 prefetch on the 256MB x stream (2 outstanding loads/thread),
//      depth-1 prefetch on the L2-hot iscale vector, NT load/store on the
//      big streams. No transcendentals in the hot loop.

typedef float f32x4 __attribute__((ext_vector_type(4)));

__device__ __forceinline__ float sigmoidf_acc(float v) {
    return 1.0f / (1.0f + expf(-v));
}

__global__ __launch_bounds__(256) void glif_iscale_kernel(
    const float* __restrict__ conduct,
    const float* __restrict__ beta,
    float* __restrict__ iscale,
    int TC4, int C4)
{
#pragma clang fp contract(off)
    int idx = blockIdx.x * blockDim.x + threadIdx.x;
    if (idx >= TC4) return;
    int c4 = idx & (C4 - 1);

    const f32x4 bev = reinterpret_cast<const f32x4*>(beta)[c4];
    const f32x4 cv  = reinterpret_cast<const f32x4*>(conduct)[idx];

    f32x4 ov;
    #pragma unroll
    for (int j = 0; j < 4; ++j) {
        float be = bev[j] > 0.0f ? 1.0f : 0.0f;
        float ct = sigmoidf_acc(cv[j]);
        ov[j] = 1.0f - be * (1.0f - ct);   // exact ref expression order
    }
    reinterpret_cast<f32x4*>(iscale)[idx] = ov;
}

__global__ __launch_bounds__(256) void glif_fwd_kernel(
    const float* __restrict__ x,
    const float* __restrict__ tau,
    const float* __restrict__ Vth,
    const float* __restrict__ leak,
    const float* __restrict__ reVth,
    const float* __restrict__ alpha,
    const float* __restrict__ gamma_,
    const float* __restrict__ iscale,
    float* __restrict__ out,
    int BC4, int C4, int T)
{
#pragma clang fp contract(off)
    int idx = blockIdx.x * blockDim.x + threadIdx.x;
    if (idx >= BC4) return;
    int c4 = idx & (C4 - 1);

    const f32x4 alv = reinterpret_cast<const f32x4*>(alpha)[c4];
    const f32x4 gav = reinterpret_cast<const f32x4*>(gamma_)[c4];
    const f32x4 tav = reinterpret_cast<const f32x4*>(tau  )[c4];
    const f32x4 vtv = reinterpret_cast<const f32x4*>(Vth  )[c4];
    const f32x4 lkv = reinterpret_cast<const f32x4*>(leak )[c4];
    const f32x4 rvv = reinterpret_cast<const f32x4*>(reVth)[c4];

    float decay[4], leakt[4], vth_s[4], rvc[4], ga[4];
    #pragma unroll
    for (int j = 0; j < 4; ++j) {
        float al = alv[j] > 0.0f ? 1.0f : 0.0f;
        ga[j]    = gav[j] > 0.0f ? 1.0f : 0.0f;
        float tau_s   = sigmoidf_acc(tav[j]);
        float vth_sj  = sigmoidf_acc(vtv[j]);
        float leak_s  = sigmoidf_acc(lkv[j]);
        float reVth_s = sigmoidf_acc(rvv[j]);
        decay[j] = 1.0f - al * (1.0f - tau_s);
        leakt[j] = (1.0f - al) * leak_s;
        vth_s[j] = vth_sj;
        rvc[j]   = (1.0f - ga[j]) * reVth_s;
    }

    float u[4] = {0.0f, 0.0f, 0.0f, 0.0f};
    float o[4] = {0.0f, 0.0f, 0.0f, 0.0f};

    const f32x4* __restrict__ x4  = reinterpret_cast<const f32x4*>(x);
    const f32x4* __restrict__ is4 = reinterpret_cast<const f32x4*>(iscale);
    f32x4* __restrict__ o4 = reinterpret_cast<f32x4*>(out);

    const size_t base = (size_t)idx;
    const size_t strd = (size_t)BC4;

    // ---- software pipeline: depth-2 on x, depth-1 on iscale ----
    f32x4 xp0 = __builtin_nontemporal_load(&x4[base]);              // t = 0
    f32x4 xp1;
    if (T > 1) xp1 = __builtin_nontemporal_load(&x4[base + strd]);  // t = 1
    f32x4 ivc = is4[c4];                                            // t = 0

    for (int t = 0; t < T; ++t) {
        // issue prefetches first (wave-uniform guards, no divergence)
        f32x4 xp2;
        if (t + 2 < T)
            xp2 = __builtin_nontemporal_load(&x4[base + (size_t)(t + 2) * strd]);
        f32x4 ivn = ivc;
        if (t + 1 < T)
            ivn = is4[(size_t)(t + 1) * (size_t)C4 + (size_t)c4];

        f32x4 ov;
        #pragma unroll
        for (int j = 0; j < 4; ++j) {
            float I  = xp0[j] * ivc[j];
            float un = decay[j] * u[j] * (1.0f - ga[j] * o[j]) - leakt[j] + I
                       - rvc[j] * o[j];
            float on = (un - vth_s[j] >= 0.0f) ? 1.0f : 0.0f;
            u[j] = un;
            o[j] = on;
            ov[j] = on;
        }

        __builtin_nontemporal_store(ov, &o4[base + (size_t)t * strd]);

        xp0 = xp1;
        xp1 = xp2;
        ivc = ivn;
    }
}

extern "C" void kernel_launch(void* const* d_in, const int* in_sizes, int n_in,
                              void* d_out, int out_size, void* d_ws, size_t ws_size,
                              hipStream_t stream) {
    const float* x       = (const float*)d_in[0];
    const float* tau     = (const float*)d_in[1];
    const float* Vth     = (const float*)d_in[2];
    const float* leak    = (const float*)d_in[3];
    const float* reVth   = (const float*)d_in[4];
    const float* conduct = (const float*)d_in[5];
    const float* alpha   = (const float*)d_in[6];
    const float* beta    = (const float*)d_in[7];
    const float* gamma_  = (const float*)d_in[8];
    float* out = (float*)d_out;

    const int C  = in_sizes[1];                        // 1024
    const int T  = in_sizes[5] / C;                    // 16
    const long long BC = (long long)in_sizes[0] / T;   // B*C
    const int BC4 = (int)(BC / 4);
    const int C4  = C / 4;
    const int TC4 = T * C4;

    const int block = 256;
    const int grid  = (BC4 + block - 1) / block;

    float* iscale = (float*)d_ws;  // needs T*C*4 = 64KB
    glif_iscale_kernel<<<(TC4 + block - 1) / block, block, 0, stream>>>(
        conduct, beta, iscale, TC4, C4);
    glif_fwd_kernel<<<grid, block, 0, stream>>>(
        x, tau, Vth, leak, reVth, alpha, gamma_, iscale, out, BC4, C4, T);
}

// Round 5
// 101.376 us; speedup vs baseline: 1.1407x; 1.0717x over previous
//
#include <hip/hip_runtime.h>
#include <math.h>

// GLIF forward, two-kernel version:
//  K1: iscale[t][c] = 1 - be_c*(1 - sigmoid(conduct[t][c]))   (64KB)
//      + per-channel derived params decay/leak_term/Vth_s/rvc/ga (20KB)
//      all into d_ws. K2 has ZERO transcendentals, 5 param vec-loads.
//  K2: scan over T; one thread owns 4 channels of one batch row.
//      NT loads on the 256MB x stream (read-once, keep L2 for tables),
//      PLAIN stores on out (let L2 write-combine like the 7TB/s fills).

typedef float f32x4 __attribute__((ext_vector_type(4)));

__device__ __forceinline__ float sigmoidf_acc(float v) {
    return 1.0f / (1.0f + expf(-v));
}

__global__ __launch_bounds__(256) void glif_prep_kernel(
    const float* __restrict__ conduct,
    const float* __restrict__ beta,
    const float* __restrict__ tau,
    const float* __restrict__ Vth,
    const float* __restrict__ leak,
    const float* __restrict__ reVth,
    const float* __restrict__ alpha,
    const float* __restrict__ gamma_,
    float* __restrict__ ws,      // [T*C] iscale, then 5 x [C] params
    int TC4, int C4)
{
#pragma clang fp contract(off)
    int idx = blockIdx.x * blockDim.x + threadIdx.x;
    if (idx >= TC4) return;
    int c4 = idx & (C4 - 1);

    // iscale[t][c]
    const f32x4 bev = reinterpret_cast<const f32x4*>(beta)[c4];
    const f32x4 cv  = reinterpret_cast<const f32x4*>(conduct)[idx];
    f32x4 ov;
    #pragma unroll
    for (int j = 0; j < 4; ++j) {
        float be = bev[j] > 0.0f ? 1.0f : 0.0f;
        float ct = sigmoidf_acc(cv[j]);
        ov[j] = 1.0f - be * (1.0f - ct);   // exact ref expression order
    }
    reinterpret_cast<f32x4*>(ws)[idx] = ov;

    // per-channel derived params (first C4 threads only)
    if (idx < C4) {
        const int TC = TC4 * 4;
        const f32x4 alv = reinterpret_cast<const f32x4*>(alpha)[c4];
        const f32x4 gav = reinterpret_cast<const f32x4*>(gamma_)[c4];
        const f32x4 tav = reinterpret_cast<const f32x4*>(tau  )[c4];
        const f32x4 vtv = reinterpret_cast<const f32x4*>(Vth  )[c4];
        const f32x4 lkv = reinterpret_cast<const f32x4*>(leak )[c4];
        const f32x4 rvv = reinterpret_cast<const f32x4*>(reVth)[c4];

        f32x4 decay, leakt, vth_s, rvc, ga;
        #pragma unroll
        for (int j = 0; j < 4; ++j) {
            float al = alv[j] > 0.0f ? 1.0f : 0.0f;
            float g  = gav[j] > 0.0f ? 1.0f : 0.0f;
            float tau_s   = sigmoidf_acc(tav[j]);
            float vth_sj  = sigmoidf_acc(vtv[j]);
            float leak_s  = sigmoidf_acc(lkv[j]);
            float reVth_s = sigmoidf_acc(rvv[j]);
            decay[j] = 1.0f - al * (1.0f - tau_s);
            leakt[j] = (1.0f - al) * leak_s;
            vth_s[j] = vth_sj;
            rvc[j]   = (1.0f - g) * reVth_s;
            ga[j]    = g;
        }
        f32x4* p = reinterpret_cast<f32x4*>(ws + TC);
        p[0 * C4 + c4] = decay;
        p[1 * C4 + c4] = leakt;
        p[2 * C4 + c4] = vth_s;
        p[3 * C4 + c4] = rvc;
        p[4 * C4 + c4] = ga;
    }
}

__global__ __launch_bounds__(256) void glif_fwd_kernel(
    const float* __restrict__ x,
    const float* __restrict__ ws,   // iscale [T*C] + params 5x[C]
    float* __restrict__ out,
    int BC4, int C4, int T)
{
#pragma clang fp contract(off)
    int idx = blockIdx.x * blockDim.x + threadIdx.x;
    if (idx >= BC4) return;
    int c4 = idx & (C4 - 1);
    const int TC4 = T * C4;

    const f32x4* __restrict__ p = reinterpret_cast<const f32x4*>(ws) + TC4;
    const f32x4 decay = p[0 * C4 + c4];
    const f32x4 leakt = p[1 * C4 + c4];
    const f32x4 vth_s = p[2 * C4 + c4];
    const f32x4 rvc   = p[3 * C4 + c4];
    const f32x4 ga    = p[4 * C4 + c4];

    float u[4] = {0.0f, 0.0f, 0.0f, 0.0f};
    float o[4] = {0.0f, 0.0f, 0.0f, 0.0f};

    const f32x4* __restrict__ x4  = reinterpret_cast<const f32x4*>(x);
    const f32x4* __restrict__ is4 = reinterpret_cast<const f32x4*>(ws);
    f32x4* __restrict__ o4 = reinterpret_cast<f32x4*>(out);

    const size_t base = (size_t)idx;
    const size_t strd = (size_t)BC4;

    // ---- software pipeline: depth-2 on x, depth-1 on iscale ----
    f32x4 xp0 = __builtin_nontemporal_load(&x4[base]);              // t = 0
    f32x4 xp1;
    if (T > 1) xp1 = __builtin_nontemporal_load(&x4[base + strd]);  // t = 1
    f32x4 ivc = is4[c4];                                            // t = 0

    for (int t = 0; t < T; ++t) {
        f32x4 xp2;
        if (t + 2 < T)
            xp2 = __builtin_nontemporal_load(&x4[base + (size_t)(t + 2) * strd]);
        f32x4 ivn = ivc;
        if (t + 1 < T)
            ivn = is4[(size_t)(t + 1) * (size_t)C4 + (size_t)c4];

        f32x4 ov;
        #pragma unroll
        for (int j = 0; j < 4; ++j) {
            float I  = xp0[j] * ivc[j];
            float un = decay[j] * u[j] * (1.0f - ga[j] * o[j]) - leakt[j] + I
                       - rvc[j] * o[j];
            float on = (un - vth_s[j] >= 0.0f) ? 1.0f : 0.0f;
            u[j] = un;
            o[j] = on;
            ov[j] = on;
        }

        o4[base + (size_t)t * strd] = ov;   // plain store (L2 write-combine)

        xp0 = xp1;
        xp1 = xp2;
        ivc = ivn;
    }
}

extern "C" void kernel_launch(void* const* d_in, const int* in_sizes, int n_in,
                              void* d_out, int out_size, void* d_ws, size_t ws_size,
                              hipStream_t stream) {
    const float* x       = (const float*)d_in[0];
    const float* tau     = (const float*)d_in[1];
    const float* Vth     = (const float*)d_in[2];
    const float* leak    = (const float*)d_in[3];
    const float* reVth   = (const float*)d_in[4];
    const float* conduct = (const float*)d_in[5];
    const float* alpha   = (const float*)d_in[6];
    const float* beta    = (const float*)d_in[7];
    const float* gamma_  = (const float*)d_in[8];
    float* out = (float*)d_out;

    const int C  = in_sizes[1];                        // 1024
    const int T  = in_sizes[5] / C;                    // 16
    const long long BC = (long long)in_sizes[0] / T;   // B*C
    const int BC4 = (int)(BC / 4);
    const int C4  = C / 4;
    const int TC4 = T * C4;

    const int block = 256;

    float* ws = (float*)d_ws;  // needs (T*C + 5*C)*4 = 84KB
    glif_prep_kernel<<<(TC4 + block - 1) / block, block, 0, stream>>>(
        conduct, beta, tau, Vth, leak, reVth, alpha, gamma_, ws, TC4, C4);
    glif_fwd_kernel<<<(BC4 + block - 1) / block, block, 0, stream>>>(
        x, ws, out, BC4, C4, T);
}